// Round 13
// baseline (449.902 us; speedup 1.0000x reference)
//
#include <hip/hip_runtime.h>
#include <math.h>

#define N_TOKENS 16384
#define D_MODEL  4096
#define N_EXP    64

#define TOKB  64                 // tokens per block
#define NWV   16                 // waves per block (1024 threads)
#define NSL   8                  // k-slices
#define KSL   (D_MODEL / NSL)    // 512 k per wave
#define CHK   16                 // k per chunk
#define NCH   (KSL / CHK)        // 32 chunks
#define XLD   68                 // x-tile row stride (64 + 4 pad)
#define XTS   (CHK * XLD)        // 1088 floats per buffer
#define WVS   (2 * XTS)          // 2176 floats per wave (double-buffered)
#define PPAD  36                 // partial-tile expert stride (16B-aligned)
#define PFOFF (NWV * TOKB * PPAD) // 36864 floats
#define NBLK  (N_TOKENS / TOKB)  // 256 blocks = 1/CU -> 4 waves/SIMD

// ---------------------------------------------------------------------------
// Pre-pass: w[64][4096] -> wT[4096][64] (k-major). A k-row's 64 experts are
// contiguous -> per-k expert-half = 32 uniform floats -> s_load_dwordx16.
// ---------------------------------------------------------------------------
__global__ void __launch_bounds__(256)
transpose_w(const float* __restrict__ w, float* __restrict__ wt) {
    __shared__ float t[64][65];
    const int k0 = blockIdx.x * 64;
    const int kc = (threadIdx.x & 15) * 4;
    const int e0 = threadIdx.x >> 4;         // 0..15
#pragma unroll
    for (int p = 0; p < 4; ++p) {
        int e = p * 16 + e0;
        float4 v = *(const float4*)(w + (size_t)e * D_MODEL + k0 + kc);
        t[kc + 0][e] = v.x; t[kc + 1][e] = v.y;
        t[kc + 2][e] = v.z; t[kc + 3][e] = v.w;
    }
    __syncthreads();
    const int kr = threadIdx.x >> 2;         // 0..63
    const int ec = (threadIdx.x & 3) * 16;
#pragma unroll
    for (int j = 0; j < 4; ++j) {
        float4 v = make_float4(t[kr][ec + j * 4 + 0], t[kr][ec + j * 4 + 1],
                               t[kr][ec + j * 4 + 2], t[kr][ec + j * 4 + 3]);
        *(float4*)(wt + (size_t)(k0 + kr) * N_EXP + ec + j * 4) = v;
    }
}

// ---------------------------------------------------------------------------
// Fused router — LDS-transposed x (coalesced, TA-cheap) + scalar-pipe w.
// Rounds 8-12 diagnosis: (a) x gather = 64 lines/instr -> TA co-critical
// with VALU (~4096 lines vs ~4096 FMA-cyc per CU chunk-window); (b) the
// allocator targets <=64 VGPR (2-block co-residency the 155KB LDS forbids)
// and always sinks the 16 prefetch regs (VGPR=52 across 3 rounds).
// This version:
//   - per chunk each wave stages its PRIVATE x-tile [16k][64tok+4] with 4
//     coalesced float4 loads (16 lines/instr, 4x less TA) + 16 b32 ds_writes
//     (banks 2-way = free); no main-loop barriers (per-wave tiles)
//   - compute: 16 upfront ds_read_b32 (stride-1 free; ~93 LDS-cyc vs 1024
//     FMA-cyc) -> ONE lgkmcnt drain per chunk (round 9's per-k drain = 512x
//     was the failure) -> 512-FMA block with w rows via s_load from L2-hot wT
//   - launch_bounds(1024,4): request the 128-VGPR budget explicitly
//   - even if loads sink to the ds_write site, the stall is covered by 4
//     independent waves/SIMD (no barrier correlation)
// Epilogue: barrier, 16 partial tiles [64][32] stride 36, 8-slice reduce,
// ballot-argmax softmax/top-2 (ties -> lowest index), per-block p/f sums.
// ---------------------------------------------------------------------------
__global__ void __launch_bounds__(1024, 4)
router_fused(const float* __restrict__ x, const float* __restrict__ wt,
             float* __restrict__ out, float* __restrict__ block_sums) {
    __shared__ float smem[PFOFF + 2 * NWV * 64];   // 38912 floats = 155648 B

    const int tid  = threadIdx.x;
    const int wid  = tid >> 6;
    const int lane = tid & 63;               // token within block (compute)
    const int tok0 = blockIdx.x * TOKB;

    const int wid_u = __builtin_amdgcn_readfirstlane(wid);
    const int h = wid_u & 1;                 // expert half: experts h*32..+31
    const int s = wid_u >> 1;                // k-slice: k in [s*512, s*512+512)

    float* xtile = smem + wid * WVS;         // private double-buffered x tile

    const int sr = lane >> 2;                // staging row 0..15
    const int sq = lane & 3;                 // staging k-quad 0..3

    const float* xg = x + (size_t)(tok0 + sr) * D_MODEL + s * KSL + sq * 4;
    const float* wr = wt + (size_t)s * KSL * N_EXP + h * 32;   // uniform

    float acc[32] = {};
    float4 v0, v1, v2, v3;
    float x0, x1, x2, x3, x4, x5, x6, x7, x8, x9, x10, x11, x12, x13, x14, x15;

#define GLOAD(g) do {                                          \
        const float* xp_ = xg + (size_t)(g) * CHK;             \
        v0 = *(const float4*)(xp_);                            \
        v1 = *(const float4*)(xp_ + (size_t)16 * D_MODEL);     \
        v2 = *(const float4*)(xp_ + (size_t)32 * D_MODEL);     \
        v3 = *(const float4*)(xp_ + (size_t)48 * D_MODEL);     \
    } while (0)

    // kk = sq*4+i, col = sr+16m: banks (4kk + col)%32 -> 2 lanes/bank (free)
#define XWRITE(b) do {                                         \
        float* t_ = xtile + (b) * XTS + (sq * 4) * XLD + sr;   \
        t_[0 * XLD +  0] = v0.x; t_[1 * XLD +  0] = v0.y;      \
        t_[2 * XLD +  0] = v0.z; t_[3 * XLD +  0] = v0.w;      \
        t_[0 * XLD + 16] = v1.x; t_[1 * XLD + 16] = v1.y;      \
        t_[2 * XLD + 16] = v1.z; t_[3 * XLD + 16] = v1.w;      \
        t_[0 * XLD + 32] = v2.x; t_[1 * XLD + 32] = v2.y;      \
        t_[2 * XLD + 32] = v2.z; t_[3 * XLD + 32] = v2.w;      \
        t_[0 * XLD + 48] = v3.x; t_[1 * XLD + 48] = v3.y;      \
        t_[2 * XLD + 48] = v3.z; t_[3 * XLD + 48] = v3.w;      \
    } while (0)

#define XREAD(b) do {                                          \
        const float* t_ = xtile + (b) * XTS + lane;            \
        x0  = t_[ 0 * XLD]; x1  = t_[ 1 * XLD];                \
        x2  = t_[ 2 * XLD]; x3  = t_[ 3 * XLD];                \
        x4  = t_[ 4 * XLD]; x5  = t_[ 5 * XLD];                \
        x6  = t_[ 6 * XLD]; x7  = t_[ 7 * XLD];                \
        x8  = t_[ 8 * XLD]; x9  = t_[ 9 * XLD];                \
        x10 = t_[10 * XLD]; x11 = t_[11 * XLD];                \
        x12 = t_[12 * XLD]; x13 = t_[13 * XLD];                \
        x14 = t_[14 * XLD]; x15 = t_[15 * XLD];                \
    } while (0)

#define K_STEP(wg, kidx, xv) do {                              \
        const float* wk_ = (wg) + (kidx) * N_EXP;              \
        const float xk_ = (xv);                                \
        _Pragma("unroll")                                      \
        for (int e = 0; e < 32; ++e)                           \
            acc[e] = fmaf(wk_[e], xk_, acc[e]);                \
    } while (0)

#define CHUNK_FMA(g) do {                                      \
        const float* wg_ = wr + (size_t)(g) * CHK * N_EXP;     \
        K_STEP(wg_,  0, x0);  K_STEP(wg_,  1, x1);             \
        K_STEP(wg_,  2, x2);  K_STEP(wg_,  3, x3);             \
        K_STEP(wg_,  4, x4);  K_STEP(wg_,  5, x5);             \
        K_STEP(wg_,  6, x6);  K_STEP(wg_,  7, x7);             \
        K_STEP(wg_,  8, x8);  K_STEP(wg_,  9, x9);             \
        K_STEP(wg_, 10, x10); K_STEP(wg_, 11, x11);            \
        K_STEP(wg_, 12, x12); K_STEP(wg_, 13, x13);            \
        K_STEP(wg_, 14, x14); K_STEP(wg_, 15, x15);            \
    } while (0)

    // prologue: stage chunk 0 into buffer 0
    GLOAD(0);
    XWRITE(0);

#pragma unroll 1
    for (int g = 0; g < NCH - 1; ++g) {
        const int cur = g & 1;
        const int nxt = cur ^ 1;

        GLOAD(g + 1);                         // issue next chunk's loads
        __builtin_amdgcn_sched_barrier(0);    // keep them above the FMAs
        XREAD(cur);                           // 16 ds_read_b32, one drain
        CHUNK_FMA(g);                         // 512 FMA, w via s_load
        XWRITE(nxt);                          // vmcnt wait lands here
    }
    XREAD((NCH - 1) & 1);
    CHUNK_FMA(NCH - 1);

    // ---- epilogue: all waves done, then k-slice reduce + softmax/top2 ----
    __syncthreads();                          // part[] overlays staging tiles
    {
        float* tp = smem + (size_t)(wid * TOKB + lane) * PPAD;
#pragma unroll
        for (int e0 = 0; e0 < 32; e0 += 4)
            *(float4*)(tp + e0) = make_float4(acc[e0], acc[e0 + 1],
                                              acc[e0 + 2], acc[e0 + 3]);
    }
    __syncthreads();

    float p_acc = 0.f, f_acc = 0.f;          // lane = expert now
    const int he = lane >> 5;                // this expert's half
    const int ew = lane & 31;
#pragma unroll 1
    for (int it = 0; it < 4; ++it) {
        const int tl = wid * 4 + it;         // local token (16 waves x 4)
        float logit = 0.f;
#pragma unroll
        for (int sl = 0; sl < NSL; ++sl)
            logit += smem[(size_t)((2 * sl + he) * TOKB + tl) * PPAD + ew];

        // top-1: value max-reduce, then ballot -> lowest tied index
        float m = logit;
#pragma unroll
        for (int off = 32; off; off >>= 1)
            m = fmaxf(m, __shfl_xor(m, off, 64));
        unsigned long long b1 = __ballot(logit == m);
        int i1 = __ffsll(b1) - 1;

        float p = expf(logit - m);
        float denom = p;
#pragma unroll
        for (int off = 32; off; off >>= 1)
            denom += __shfl_xor(denom, off, 64);

        p_acc += p / denom;                  // router_probs[token][lane]
        if (lane == i1) f_acc += 1.f;

        // top-2: mask i1, repeat
        float lx = (lane == i1) ? -__builtin_inff() : logit;
        float m2 = lx;
#pragma unroll
        for (int off = 32; off; off >>= 1)
            m2 = fmaxf(m2, __shfl_xor(m2, off, 64));
        unsigned long long b2 = __ballot(lx == m2);
        int i2 = __ffsll(b2) - 1;

        if (lane == 0) {
            float p1 = 1.0f / denom;                 // exp(m-m)/denom
            float p2 = expf(m2 - m) / denom;
            float s12 = p1 + p2;
            int token = tok0 + tl;
            ((float2*)out)[token] = make_float2(p1 / s12, p2 / s12);
            ((float2*)(out + 2 * N_TOKENS))[token] =
                make_float2((float)i1, (float)i2);
        }
    }

    // block-level p/f sums -> block_sums (no atomics)
    float* pf = smem + PFOFF;                // [0,1024): p, [1024,2048): f
    pf[wid * 64 + lane]        = p_acc;
    pf[1024 + wid * 64 + lane] = f_acc;
    __syncthreads();
    if (tid < N_EXP) {
        float ps = 0.f, fs = 0.f;
#pragma unroll
        for (int hh = 0; hh < NWV; ++hh) {
            ps += pf[hh * 64 + tid];
            fs += pf[1024 + hh * 64 + tid];
        }
        block_sums[(size_t)blockIdx.x * 128 + tid]      = ps;
        block_sums[(size_t)blockIdx.x * 128 + 64 + tid] = fs;
    }
}

// ---------------------------------------------------------------------------
// Final: reduce 256 blocks' p/f sums, loss = 0.01 * sum_e (f_e/N)*(p_e/N).
// ---------------------------------------------------------------------------
__global__ void __launch_bounds__(256)
router_final(const float* __restrict__ block_sums, float* __restrict__ out) {
    __shared__ float sp[4][N_EXP];
    __shared__ float sf[4][N_EXP];

    int tid  = threadIdx.x;
    int wv   = tid >> 6;
    int lane = tid & 63;

    float ps = 0.f, fs = 0.f;
#pragma unroll 8
    for (int b = wv * (NBLK / 4); b < (wv + 1) * (NBLK / 4); ++b) {
        ps += block_sums[(size_t)b * 128 + lane];
        fs += block_sums[(size_t)b * 128 + 64 + lane];
    }
    sp[wv][lane] = ps;
    sf[wv][lane] = fs;
    __syncthreads();

    if (tid < N_EXP) {
        float pt = sp[0][tid] + sp[1][tid] + sp[2][tid] + sp[3][tid];
        float ft = sf[0][tid] + sf[1][tid] + sf[2][tid] + sf[3][tid];
        float v = pt * ft;
#pragma unroll
        for (int off = 1; off < 64; off <<= 1)
            v += __shfl_xor(v, off, 64);
        if (tid == 0)
            out[4 * N_TOKENS] = 0.01f * v / ((float)N_TOKENS * (float)N_TOKENS);
    }
}

// ---------------------------------------------------------------------------
extern "C" void kernel_launch(void* const* d_in, const int* in_sizes, int n_in,
                              void* d_out, int out_size, void* d_ws, size_t ws_size,
                              hipStream_t stream) {
    (void)in_sizes; (void)n_in; (void)out_size; (void)ws_size;
    const float* x = (const float*)d_in[0];
    const float* w = (const float*)d_in[1];
    float* out = (float*)d_out;

    float* wT = (float*)d_ws;                            // 4096*64*4 = 1 MB
    float* block_sums = wT + (size_t)D_MODEL * N_EXP;    // 256*128*4 = 128 KB

    transpose_w<<<D_MODEL / 64, 256, 0, stream>>>(w, wT);
    router_fused<<<NBLK, 1024, 0, stream>>>(x, wT, out, block_sums);
    router_final<<<1, 256, 0, stream>>>(block_sums, out);
}